// Round 1
// baseline (520.058 us; speedup 1.0000x reference)
//
#include <hip/hip_runtime.h>
#include <math.h>

#define NN 4096
#define LOG2E 1.4426950408889634f

// workspace layout (float offsets)
#define OFF_COMB   0u          // 4096*96 = 393216
#define OFF_HMAT   393216u     // 4096*64 = 262144
#define OFF_F1     655360u     // 4096*2
#define OFF_F2     663552u     // 4096*2
#define OFF_MAXF2  671744u     // 2 (+pad)
#define OFF_W2     671760u     // 32*96 = 3072
#define OFF_B2     674832u     // 96
#define OFF_PART   675840u     // slots*4096*64, then lpart slots*4096*2

// ---------------- Kernel 1: embeddings + GAT projection + f1/f2 ----------------
__global__ __launch_bounds__(128) void k_embed(
    const float* __restrict__ spatial, const float* __restrict__ genomic,
    const float* __restrict__ temporal,
    const float* __restrict__ sp_w, const float* __restrict__ sp_b,
    const float* __restrict__ sp_lg, const float* __restrict__ sp_lb,
    const float* __restrict__ ge_w, const float* __restrict__ ge_b,
    const float* __restrict__ ge_lg, const float* __restrict__ ge_lb,
    const float* __restrict__ te_w, const float* __restrict__ te_b,
    const float* __restrict__ te_lg, const float* __restrict__ te_lb,
    const float* __restrict__ gat_w, const float* __restrict__ gat_a,
    float* __restrict__ ws)
{
  int row = blockIdx.x;
  int t = threadIdx.x;
  __shared__ float comb[96];
  __shared__ float hbuf[64];

  if (t < 96) {
    int g = t >> 5, c = t & 31;
    float x;
    if (g == 0) {
      const float* in = spatial + (size_t)row * 256;
      float a = sp_b[c];
      for (int k = 0; k < 256; k++) a = fmaf(in[k], sp_w[k * 32 + c], a);
      x = a;
    } else if (g == 1) {
      const float* in = genomic + (size_t)row * 8;
      float a = ge_b[c];
      for (int k = 0; k < 8; k++) a = fmaf(in[k], ge_w[k * 32 + c], a);
      x = a;
    } else {
      const float* in = temporal + (size_t)row * 64;
      float a = te_b[c];
      for (int k = 0; k < 64; k++) a = fmaf(in[k], te_w[k * 32 + c], a);
      x = a;
    }
    // LayerNorm over the 32 lanes of this group (groups are wave-aligned)
    float s1 = x, s2 = x * x;
    for (int m = 1; m < 32; m <<= 1) {
      s1 += __shfl_xor(s1, m, 32);
      s2 += __shfl_xor(s2, m, 32);
    }
    float mean = s1 * (1.f / 32.f);
    float var  = s2 * (1.f / 32.f) - mean * mean;
    float inv  = rsqrtf(var + 1e-5f);
    const float* lg = (g == 0) ? sp_lg : (g == 1) ? ge_lg : te_lg;
    const float* lb = (g == 0) ? sp_lb : (g == 1) ? ge_lb : te_lb;
    float y = (x - mean) * inv * lg[c] + lb[c];
    y = fmaxf(y, 0.f);
    comb[t] = y;
    ws[OFF_COMB + (size_t)row * 96 + t] = y;
  }
  __syncthreads();
  if (t < 64) {
    float a = 0.f;
    for (int r = 0; r < 96; r++) a = fmaf(comb[r], gat_w[r * 64 + t], a);
    hbuf[t] = a;
    ws[OFF_HMAT + (size_t)row * 64 + t] = a;
  }
  __syncthreads();
  if (t < 4) {
    int head = t & 1;
    const float* av = gat_a + ((t >> 1) ? 32 : 0);
    float a = 0.f;
    for (int d = 0; d < 32; d++) a = fmaf(hbuf[head * 32 + d], av[d], a);
    if ((t >> 1) == 0) ws[OFF_F1 + (size_t)row * 2 + head] = a;
    else               ws[OFF_F2 + (size_t)row * 2 + head] = a;
  }
}

// -------- Kernel 1b: fold mha (tile->v->attn collapses to 32x96), maxf2 --------
__global__ __launch_bounds__(128) void k_prep(
    const float* __restrict__ mha_iw, const float* __restrict__ mha_ib,
    const float* __restrict__ mha_ow, const float* __restrict__ mha_ob,
    float* __restrict__ ws)
{
  int b = blockIdx.x, t = threadIdx.x;
  if (b < 32) {
    if (t < 96) {
      // W2[b][t] = sum_r (sum_m iw[b+32m][192+r]) * ow[r][t]
      float a = 0.f;
      for (int r = 0; r < 96; r++) {
        float fw = mha_iw[(b)      * 288 + 192 + r]
                 + mha_iw[(b + 32) * 288 + 192 + r]
                 + mha_iw[(b + 64) * 288 + 192 + r];
        a = fmaf(fw, mha_ow[r * 96 + t], a);
      }
      ws[OFF_W2 + b * 96 + t] = a;
    }
  } else if (b == 32) {
    if (t < 96) {
      float a = mha_ob[t];
      for (int r = 0; r < 96; r++) a = fmaf(mha_ib[192 + r], mha_ow[r * 96 + t], a);
      ws[OFF_B2 + t] = a;
    }
  } else {
    __shared__ float red[128 * 2];
    float m0 = -1e30f, m1 = -1e30f;
    for (int k = t; k < NN; k += 128) {
      m0 = fmaxf(m0, ws[OFF_F2 + (size_t)k * 2]);
      m1 = fmaxf(m1, ws[OFF_F2 + (size_t)k * 2 + 1]);
    }
    red[t * 2] = m0; red[t * 2 + 1] = m1;
    __syncthreads();
    if (t < 2) {
      float m = -1e30f;
      for (int k = 0; k < 128; k++) m = fmaxf(m, red[k * 2 + t]);
      ws[OFF_MAXF2 + t] = m;
    }
  }
}

// ---------------- Kernel 2: GAT masked softmax-aggregation (the hot loop) ------
#define TJ 128
__global__ __launch_bounds__(256) void k_gat(
    const int* __restrict__ adj, float* __restrict__ ws, int NS)
{
  __shared__ __align__(16) float h_t[TJ * 64];
  __shared__ __align__(16) float f2t[2 * TJ];
  int t = threadIdx.x;
  int lane = t & 63, wave = t >> 6;
  int head = wave & 1, jh = wave >> 1;
  int i = blockIdx.x * 64 + lane;
  int slice = NN / NS;
  int j_base = blockIdx.y * slice;

  const float* f1 = ws + OFF_F1;
  const float* f2 = ws + OFF_F2;
  const float* hm = ws + OFF_HMAT;

  float f1v = f1[(size_t)i * 2 + head];
  float mf2 = ws[OFF_MAXF2 + head];
  float s = f1v + mf2;
  float shift = fmaxf(s, 0.2f * s);   // >= max_j leaky(f1+f2) since leaky monotonic
  float c0 = -shift * LOG2E;

  float acc[32];
#pragma unroll
  for (int d = 0; d < 32; d++) acc[d] = 0.f;
  float lsum = 0.f;
  const int* adjRow = adj + (size_t)i * NN;

  int ntiles = slice / TJ;
  for (int tile = 0; tile < ntiles; tile++) {
    int j0 = j_base + tile * TJ;
    __syncthreads();
    {
      const float4* src = (const float4*)(hm + (size_t)j0 * 64);
      float4* dst = (float4*)h_t;
#pragma unroll
      for (int q = 0; q < 8; q++) dst[t + 256 * q] = src[t + 256 * q];
      f2t[(t & 1) * TJ + (t >> 1)] = f2[(size_t)(j0 + (t >> 1)) * 2 + (t & 1)];
    }
    __syncthreads();
    int jb = jh * 64;
    for (int jj0 = 0; jj0 < 64; jj0 += 4) {
      int4   av = *(const int4*)(adjRow + j0 + jb + jj0);
      float4 fv = *(const float4*)(&f2t[head * TJ + jb + jj0]);
#pragma unroll
      for (int k = 0; k < 4; k++) {
        float f2s = (k == 0) ? fv.x : (k == 1) ? fv.y : (k == 2) ? fv.z : fv.w;
        int   am  = (k == 0) ? av.x : (k == 1) ? av.y : (k == 2) ? av.z : av.w;
        float e  = f1v + f2s;
        float le = fmaxf(e, 0.2f * e);          // leaky_relu
        float w  = exp2f(fmaf(le, LOG2E, c0));  // exp(le - shift)
        w = am ? w : 0.f;
        lsum += w;
        const float4* h4 = (const float4*)(h_t + (jb + jj0 + k) * 64 + head * 32);
#pragma unroll
        for (int q = 0; q < 8; q++) {
          float4 hv = h4[q];
          acc[q * 4 + 0] = fmaf(w, hv.x, acc[q * 4 + 0]);
          acc[q * 4 + 1] = fmaf(w, hv.y, acc[q * 4 + 1]);
          acc[q * 4 + 2] = fmaf(w, hv.z, acc[q * 4 + 2]);
          acc[q * 4 + 3] = fmaf(w, hv.w, acc[q * 4 + 3]);
        }
      }
    }
  }
  int slot = blockIdx.y * 2 + jh;
  float* part = ws + OFF_PART + ((size_t)(slot * NN + i)) * 64 + head * 32;
  float4* p4 = (float4*)part;
#pragma unroll
  for (int q = 0; q < 8; q++)
    p4[q] = make_float4(acc[q * 4], acc[q * 4 + 1], acc[q * 4 + 2], acc[q * 4 + 3]);
  float* lpart = ws + OFF_PART + (size_t)NS * 2 * NN * 64;
  lpart[(size_t)(slot * NN + i) * 2 + head] = lsum;
}

// ---------------- Kernel 3: reduce partials + folded tail + towers -------------
__global__ __launch_bounds__(256) void k_post(
    const float* __restrict__ gat_ow, const float* __restrict__ gat_ob,
    const float* __restrict__ gat_lg, const float* __restrict__ gat_lb,
    const float* __restrict__ m1_w, const float* __restrict__ m1_b,
    const float* __restrict__ m1_lg, const float* __restrict__ m1_lb,
    const float* __restrict__ m2_w, const float* __restrict__ m2_b,
    const float* __restrict__ m2_lg, const float* __restrict__ m2_lb,
    const float* __restrict__ m3_w, const float* __restrict__ m3_b,
    const float* __restrict__ c1_w, const float* __restrict__ c1_b,
    const float* __restrict__ c1_lg, const float* __restrict__ c1_lb,
    const float* __restrict__ c2_w, const float* __restrict__ c2_b,
    const float* __restrict__ c2_lg, const float* __restrict__ c2_lb,
    const float* __restrict__ c3_w, const float* __restrict__ c3_b,
    const float* __restrict__ ws, float* __restrict__ out, int NS)
{
  __shared__ float m1s[96 * 64];
  __shared__ float m2s[64 * 32];
  __shared__ float W2s[32 * 96];
  __shared__ float b2s[96];
  __shared__ float hv[2][64];
  __shared__ float go[2][32];
  __shared__ float fin[2][96];
  __shared__ float th1[2][2][64];
  __shared__ float lv[2][2];

  int t = threadIdx.x;
  for (int k = t; k < 96 * 64; k += 256) m1s[k] = m1_w[k];
  for (int k = t; k < 64 * 32; k += 256) m2s[k] = m2_w[k];
  for (int k = t; k < 32 * 96; k += 256) W2s[k] = ws[OFF_W2 + k];
  if (t < 96) b2s[t] = ws[OFF_B2 + t];

  int grp = t >> 7;    // two independent row-groups of 128 threads
  int t1 = t & 127;
  int slots = NS * 2;
  const float* part  = ws + OFF_PART;
  const float* lpart = part + (size_t)slots * NN * 64;
  const float* comb  = ws + OFF_COMB;

  for (int rl = 0; rl < 4; rl++) {
    int i = blockIdx.x * 8 + grp * 4 + rl;
    __syncthreads();
    float araw = 0.f;
    if (t1 < 64) {
      for (int s2 = 0; s2 < slots; s2++)
        araw += part[((size_t)(s2 * NN + i)) * 64 + t1];
    }
    if (t1 < 2) {
      float a = 0.f;
      for (int s2 = 0; s2 < slots; s2++)
        a += lpart[(size_t)(s2 * NN + i) * 2 + t1];
      lv[grp][t1] = a;
    }
    __syncthreads();
    if (t1 < 64) hv[grp][t1] = araw / lv[grp][t1 >> 5];
    __syncthreads();
    // gat_out = LN(h_out @ gat_ow + ob)
    if (t1 < 32) {
      float a = gat_ob[t1];
      for (int r = 0; r < 64; r++) a = fmaf(hv[grp][r], gat_ow[r * 32 + t1], a);
      float s1 = a, s2v = a * a;
      for (int m = 1; m < 32; m <<= 1) {
        s1 += __shfl_xor(s1, m, 32);
        s2v += __shfl_xor(s2v, m, 32);
      }
      float mean = s1 * (1.f / 32.f), var = s2v * (1.f / 32.f) - mean * mean;
      go[grp][t1] = (a - mean) * rsqrtf(var + 1e-5f) * gat_lg[t1] + gat_lb[t1];
    }
    __syncthreads();
    // final = gat_out @ W2 + b2 + combined   (mha path folded)
    if (t1 < 96) {
      float a = b2s[t1];
      for (int d = 0; d < 32; d++) a = fmaf(go[grp][d], W2s[d * 96 + t1], a);
      fin[grp][t1] = a + comb[(size_t)i * 96 + t1];
    }
    __syncthreads();
    // towers: wave (t1<64) motor, wave (t1>=64) cognitive
    {
      int tw = t1 >> 6;
      int l  = t1 & 63;
      const float* w1  = tw ? c1_w  : m1s;
      const float* b1  = tw ? c1_b  : m1_b;
      const float* lg1 = tw ? c1_lg : m1_lg;
      const float* lb1 = tw ? c1_lb : m1_lb;
      float a = b1[l];
      for (int r = 0; r < 96; r++) a = fmaf(fin[grp][r], w1[r * 64 + l], a);
      float s1 = a, s2v = a * a;
      for (int m = 1; m < 64; m <<= 1) {
        s1 += __shfl_xor(s1, m);
        s2v += __shfl_xor(s2v, m);
      }
      float mean = s1 * (1.f / 64.f), var = s2v * (1.f / 64.f) - mean * mean;
      float y = fmaxf((a - mean) * rsqrtf(var + 1e-5f) * lg1[l] + lb1[l], 0.f);
      th1[grp][tw][l] = y;
      __syncthreads();
      if (l < 32) {
        const float* w2  = tw ? c2_w  : m2s;
        const float* b2p = tw ? c2_b  : m2_b;
        const float* lg2 = tw ? c2_lg : m2_lg;
        const float* lb2 = tw ? c2_lb : m2_lb;
        float a2 = b2p[l];
        for (int r = 0; r < 64; r++) a2 = fmaf(th1[grp][tw][r], w2[r * 32 + l], a2);
        float u1 = a2, u2 = a2 * a2;
        for (int m = 1; m < 32; m <<= 1) {
          u1 += __shfl_xor(u1, m, 32);
          u2 += __shfl_xor(u2, m, 32);
        }
        float mean2 = u1 * (1.f / 32.f), var2 = u2 * (1.f / 32.f) - mean2 * mean2;
        float y2 = fmaxf((a2 - mean2) * rsqrtf(var2 + 1e-5f) * lg2[l] + lb2[l], 0.f);
        const float* w3 = tw ? c3_w : m3_w;
        float p = y2 * w3[l];
        for (int m = 1; m < 32; m <<= 1) p += __shfl_xor(p, m, 32);
        if (l == 0) {
          float v = p + (tw ? c3_b[0] : m3_b[0]);
          if (tw) out[NN + i] = 1.f / (1.f + expf(-v));
          else    out[i] = v;
        }
      }
    }
  }
}

extern "C" void kernel_launch(void* const* d_in, const int* in_sizes, int n_in,
                              void* d_out, int out_size, void* d_ws, size_t ws_size,
                              hipStream_t stream) {
  (void)in_sizes; (void)n_in; (void)out_size;
  const float* spatial  = (const float*)d_in[0];
  const float* genomic  = (const float*)d_in[1];
  const float* temporal = (const float*)d_in[2];
  const int*   adj      = (const int*)d_in[3];
  const float* sp_w = (const float*)d_in[4];
  const float* sp_b = (const float*)d_in[5];
  const float* sp_lg = (const float*)d_in[6];
  const float* sp_lb = (const float*)d_in[7];
  const float* ge_w = (const float*)d_in[8];
  const float* ge_b = (const float*)d_in[9];
  const float* ge_lg = (const float*)d_in[10];
  const float* ge_lb = (const float*)d_in[11];
  const float* te_w = (const float*)d_in[12];
  const float* te_b = (const float*)d_in[13];
  const float* te_lg = (const float*)d_in[14];
  const float* te_lb = (const float*)d_in[15];
  const float* gat_w = (const float*)d_in[16];
  const float* gat_a = (const float*)d_in[17];
  const float* gat_ow = (const float*)d_in[18];
  const float* gat_ob = (const float*)d_in[19];
  const float* gat_lg = (const float*)d_in[20];
  const float* gat_lb = (const float*)d_in[21];
  const float* mha_iw = (const float*)d_in[22];
  const float* mha_ib = (const float*)d_in[23];
  const float* mha_ow = (const float*)d_in[24];
  const float* mha_ob = (const float*)d_in[25];
  const float* m1_w = (const float*)d_in[26];
  const float* m1_b = (const float*)d_in[27];
  const float* m1_lg = (const float*)d_in[28];
  const float* m1_lb = (const float*)d_in[29];
  const float* m2_w = (const float*)d_in[30];
  const float* m2_b = (const float*)d_in[31];
  const float* m2_lg = (const float*)d_in[32];
  const float* m2_lb = (const float*)d_in[33];
  const float* m3_w = (const float*)d_in[34];
  const float* m3_b = (const float*)d_in[35];
  const float* c1_w = (const float*)d_in[36];
  const float* c1_b = (const float*)d_in[37];
  const float* c1_lg = (const float*)d_in[38];
  const float* c1_lb = (const float*)d_in[39];
  const float* c2_w = (const float*)d_in[40];
  const float* c2_b = (const float*)d_in[41];
  const float* c2_lg = (const float*)d_in[42];
  const float* c2_lb = (const float*)d_in[43];
  const float* c3_w = (const float*)d_in[44];
  const float* c3_b = (const float*)d_in[45];

  float* ws  = (float*)d_ws;
  float* out = (float*)d_out;

  // pick NS (j-slices) to fit workspace: part = NS*2*4096*64, lpart = NS*2*4096*2
  int NS = 8;
  while (NS > 1) {
    size_t need = (size_t)(OFF_PART + (size_t)NS * 2 * NN * 64 + (size_t)NS * 2 * NN * 2) * 4;
    if (need <= ws_size) break;
    NS >>= 1;
  }

  k_embed<<<NN, 128, 0, stream>>>(spatial, genomic, temporal,
                                  sp_w, sp_b, sp_lg, sp_lb,
                                  ge_w, ge_b, ge_lg, ge_lb,
                                  te_w, te_b, te_lg, te_lb,
                                  gat_w, gat_a, ws);
  k_prep<<<34, 128, 0, stream>>>(mha_iw, mha_ib, mha_ow, mha_ob, ws);
  dim3 g2(NN / 64, NS);
  k_gat<<<g2, 256, 0, stream>>>(adj, ws, NS);
  k_post<<<NN / 8, 256, 0, stream>>>(gat_ow, gat_ob, gat_lg, gat_lb,
                                     m1_w, m1_b, m1_lg, m1_lb,
                                     m2_w, m2_b, m2_lg, m2_lb,
                                     m3_w, m3_b,
                                     c1_w, c1_b, c1_lg, c1_lb,
                                     c2_w, c2_b, c2_lg, c2_lb,
                                     c3_w, c3_b,
                                     ws, out, NS);
}

// Round 2
// 417.771 us; speedup vs baseline: 1.2448x; 1.2448x over previous
//
#include <hip/hip_runtime.h>
#include <math.h>

#define NN 4096
#define LOG2E 1.4426950408889634f

// workspace layout (float offsets)
#define OFF_COMB   0u          // 4096*96 = 393216
#define OFF_HMAT   393216u     // 4096*64 = 262144
#define OFF_F1     655360u     // 4096*2
#define OFF_F2     663552u     // 4096*2
#define OFF_MAXF2  671744u     // 2 (+pad to 16)
#define OFF_W2     671760u     // 32*96 = 3072
#define OFF_B2     674832u     // 96 (+pad to 674944, 8B-aligned for pack)
#define OFF_PACK   674944u     // NN*NN/32 uint32 = 524288 float-slots (2 MB)
#define OFF_PART   1199232u    // NS*2*NN*64 floats, then lpart NS*2*NN*2

// ---------------- Kernel 0: pack adjacency into bitmask ----------------
__global__ __launch_bounds__(256) void k_pack(
    const int* __restrict__ adj, unsigned long long* __restrict__ pack)
{
  size_t t = (size_t)blockIdx.x * 256 + threadIdx.x;
  unsigned long long m = __ballot(adj[t] != 0);
  if ((threadIdx.x & 63) == 0) pack[t >> 6] = m;
}

// ---------------- Kernel 1: embeddings + GAT projection + f1/f2 ----------------
__global__ __launch_bounds__(128) void k_embed(
    const float* __restrict__ spatial, const float* __restrict__ genomic,
    const float* __restrict__ temporal,
    const float* __restrict__ sp_w, const float* __restrict__ sp_b,
    const float* __restrict__ sp_lg, const float* __restrict__ sp_lb,
    const float* __restrict__ ge_w, const float* __restrict__ ge_b,
    const float* __restrict__ ge_lg, const float* __restrict__ ge_lb,
    const float* __restrict__ te_w, const float* __restrict__ te_b,
    const float* __restrict__ te_lg, const float* __restrict__ te_lb,
    const float* __restrict__ gat_w, const float* __restrict__ gat_a,
    float* __restrict__ ws)
{
  int row = blockIdx.x;
  int t = threadIdx.x;
  __shared__ float comb[96];
  __shared__ float hbuf[64];

  if (t < 96) {
    int g = t >> 5, c = t & 31;
    float x;
    if (g == 0) {
      const float* in = spatial + (size_t)row * 256;
      float a = sp_b[c];
      for (int k = 0; k < 256; k++) a = fmaf(in[k], sp_w[k * 32 + c], a);
      x = a;
    } else if (g == 1) {
      const float* in = genomic + (size_t)row * 8;
      float a = ge_b[c];
      for (int k = 0; k < 8; k++) a = fmaf(in[k], ge_w[k * 32 + c], a);
      x = a;
    } else {
      const float* in = temporal + (size_t)row * 64;
      float a = te_b[c];
      for (int k = 0; k < 64; k++) a = fmaf(in[k], te_w[k * 32 + c], a);
      x = a;
    }
    float s1 = x, s2 = x * x;
    for (int m = 1; m < 32; m <<= 1) {
      s1 += __shfl_xor(s1, m, 32);
      s2 += __shfl_xor(s2, m, 32);
    }
    float mean = s1 * (1.f / 32.f);
    float var  = s2 * (1.f / 32.f) - mean * mean;
    float inv  = rsqrtf(var + 1e-5f);
    const float* lg = (g == 0) ? sp_lg : (g == 1) ? ge_lg : te_lg;
    const float* lb = (g == 0) ? sp_lb : (g == 1) ? ge_lb : te_lb;
    float y = (x - mean) * inv * lg[c] + lb[c];
    y = fmaxf(y, 0.f);
    comb[t] = y;
    ws[OFF_COMB + (size_t)row * 96 + t] = y;
  }
  __syncthreads();
  if (t < 64) {
    float a = 0.f;
    for (int r = 0; r < 96; r++) a = fmaf(comb[r], gat_w[r * 64 + t], a);
    hbuf[t] = a;
    ws[OFF_HMAT + (size_t)row * 64 + t] = a;
  }
  __syncthreads();
  if (t < 4) {
    int head = t & 1;
    const float* av = gat_a + ((t >> 1) ? 32 : 0);
    float a = 0.f;
    for (int d = 0; d < 32; d++) a = fmaf(hbuf[head * 32 + d], av[d], a);
    if ((t >> 1) == 0) ws[OFF_F1 + (size_t)row * 2 + head] = a;
    else               ws[OFF_F2 + (size_t)row * 2 + head] = a;
  }
}

// -------- Kernel 1b: fold mha (tile->v->attn collapses to 32x96), maxf2 --------
__global__ __launch_bounds__(128) void k_prep(
    const float* __restrict__ mha_iw, const float* __restrict__ mha_ib,
    const float* __restrict__ mha_ow, const float* __restrict__ mha_ob,
    float* __restrict__ ws)
{
  int b = blockIdx.x, t = threadIdx.x;
  if (b < 32) {
    if (t < 96) {
      float a = 0.f;
      for (int r = 0; r < 96; r++) {
        float fw = mha_iw[(b)      * 288 + 192 + r]
                 + mha_iw[(b + 32) * 288 + 192 + r]
                 + mha_iw[(b + 64) * 288 + 192 + r];
        a = fmaf(fw, mha_ow[r * 96 + t], a);
      }
      ws[OFF_W2 + b * 96 + t] = a;
    }
  } else if (b == 32) {
    if (t < 96) {
      float a = mha_ob[t];
      for (int r = 0; r < 96; r++) a = fmaf(mha_ib[192 + r], mha_ow[r * 96 + t], a);
      ws[OFF_B2 + t] = a;
    }
  } else {
    __shared__ float red[128 * 2];
    float m0 = -1e30f, m1 = -1e30f;
    for (int k = t; k < NN; k += 128) {
      m0 = fmaxf(m0, ws[OFF_F2 + (size_t)k * 2]);
      m1 = fmaxf(m1, ws[OFF_F2 + (size_t)k * 2 + 1]);
    }
    red[t * 2] = m0; red[t * 2 + 1] = m1;
    __syncthreads();
    if (t < 2) {
      float m = -1e30f;
      for (int k = 0; k < 128; k++) m = fmaxf(m, red[k * 2 + t]);
      ws[OFF_MAXF2 + t] = m;
    }
  }
}

// ------ Kernel 2: GAT softmax-aggregation; h[j]/f2[j] via wave-uniform s_load --
__global__ __launch_bounds__(256) void k_gat2(
    const unsigned long long* __restrict__ pack,
    const float* __restrict__ hmat,
    const float* __restrict__ f1,
    const float* __restrict__ f2,
    const float* __restrict__ maxf2,
    float* __restrict__ part,
    float* __restrict__ lpart, int NS)
{
  int t = threadIdx.x;
  int lane = t & 63, wv = t >> 6;
  int head = wv & 1, jh = wv >> 1;
  int i = blockIdx.x * 64 + lane;
  int slice = NN / NS;
  int jb = blockIdx.y * slice + jh * (slice >> 1);
  int jend = jb + (slice >> 1);

  float f1v = f1[(size_t)i * 2 + head];
  float mf2 = maxf2[head];
  float s = f1v + mf2;
  float shift = fmaxf(s, 0.2f * s);   // >= max_j leaky(f1+f2), leaky monotonic
  float c0 = -shift * LOG2E;

  float acc[32];
#pragma unroll
  for (int d = 0; d < 32; d++) acc[d] = 0.f;
  float lsum = 0.f;
  const unsigned long long* prow = pack + (size_t)i * (NN / 64);

  for (int j0 = jb; j0 < jend; j0 += 64) {
    unsigned long long qm = prow[j0 >> 6];   // per-lane 8B gather, 1 per 64 j
    const float* h0  = hmat + (size_t)j0 * 64 + head * 32;  // uniform base
    const float* f20 = f2 + (size_t)j0 * 2 + head;          // uniform base
#pragma unroll 2
    for (int jj = 0; jj < 64; jj++) {
      float f2v = f20[jj * 2];                    // wave-uniform -> s_load
      float e  = f1v + f2v;
      float le = fmaxf(e, 0.2f * e);              // leaky_relu
      float w  = __builtin_amdgcn_exp2f(fmaf(le, LOG2E, c0));
      w = ((qm >> jj) & 1ull) ? w : 0.f;
      lsum += w;
      const float* hr = h0 + (size_t)jj * 64;     // wave-uniform -> s_load x32
#pragma unroll
      for (int d = 0; d < 32; d++) acc[d] = fmaf(w, hr[d], acc[d]);
    }
  }

  int slot = blockIdx.y * 2 + jh;
  float* p = part + ((size_t)(slot * NN + i)) * 64 + head * 32;
  float4* p4 = (float4*)p;
#pragma unroll
  for (int q = 0; q < 8; q++)
    p4[q] = make_float4(acc[q * 4], acc[q * 4 + 1], acc[q * 4 + 2], acc[q * 4 + 3]);
  lpart[(size_t)(slot * NN + i) * 2 + head] = lsum;
}

// ---------------- Kernel 3: one wave per row — reduce + folded tail + towers ---
__global__ __launch_bounds__(128) void k_post2(
    const float* __restrict__ gat_ow, const float* __restrict__ gat_ob,
    const float* __restrict__ gat_lg, const float* __restrict__ gat_lb,
    const float* __restrict__ m1_w, const float* __restrict__ m1_b,
    const float* __restrict__ m1_lg, const float* __restrict__ m1_lb,
    const float* __restrict__ m2_w, const float* __restrict__ m2_b,
    const float* __restrict__ m2_lg, const float* __restrict__ m2_lb,
    const float* __restrict__ m3_w, const float* __restrict__ m3_b,
    const float* __restrict__ c1_w, const float* __restrict__ c1_b,
    const float* __restrict__ c1_lg, const float* __restrict__ c1_lb,
    const float* __restrict__ c2_w, const float* __restrict__ c2_b,
    const float* __restrict__ c2_lg, const float* __restrict__ c2_lb,
    const float* __restrict__ c3_w, const float* __restrict__ c3_b,
    const float* __restrict__ part, const float* __restrict__ lpart,
    const float* __restrict__ comb, const float* __restrict__ W2,
    const float* __restrict__ B2,
    float* __restrict__ out, int NS)
{
  int t = threadIdx.x;
  int w = t >> 6, l = t & 63;
  int i = blockIdx.x * 2 + w;
  int slots = NS * 2;

  __shared__ float sh_h[2][64];
  __shared__ float sh_go[2][32];
  __shared__ float sh_fin[2][96];
  __shared__ float sh_t1[2][2][64];

  // phase 1: reduce partials
  float a = 0.f;
  for (int s = 0; s < slots; s++) a += part[((size_t)(s * NN + i)) * 64 + l];
  float l0 = 0.f, l1 = 0.f;
  for (int s = 0; s < slots; s++) {
    l0 += lpart[(size_t)(s * NN + i) * 2];
    l1 += lpart[(size_t)(s * NN + i) * 2 + 1];
  }
  sh_h[w][l] = a / (l < 32 ? l0 : l1);
  __syncthreads();

  // phase 2: gat_out = LN32(h_out @ gat_ow + ob)
  if (l < 32) {
    float acc = gat_ob[l];
    for (int r = 0; r < 64; r++) acc = fmaf(sh_h[w][r], gat_ow[r * 32 + l], acc);
    float s1 = acc, s2 = acc * acc;
    for (int m = 1; m < 32; m <<= 1) {
      s1 += __shfl_xor(s1, m, 32);
      s2 += __shfl_xor(s2, m, 32);
    }
    float mean = s1 * (1.f / 32.f), var = s2 * (1.f / 32.f) - mean * mean;
    sh_go[w][l] = (acc - mean) * rsqrtf(var + 1e-5f) * gat_lg[l] + gat_lb[l];
  }
  __syncthreads();

  // phase 3: final = gat_out @ W2 + B2 + combined
  {
    float accA = B2[l];
    for (int d = 0; d < 32; d++) accA = fmaf(sh_go[w][d], W2[d * 96 + l], accA);
    sh_fin[w][l] = accA + comb[(size_t)i * 96 + l];
    if (l < 32) {
      float accB = B2[64 + l];
      for (int d = 0; d < 32; d++) accB = fmaf(sh_go[w][d], W2[d * 96 + 64 + l], accB);
      sh_fin[w][64 + l] = accB + comb[(size_t)i * 96 + 64 + l];
    }
  }
  __syncthreads();

  // phase 4: tower layer 1 for both towers (two accumulators)
  {
    float am = m1_b[l], ac = c1_b[l];
    for (int r = 0; r < 96; r++) {
      float f = sh_fin[w][r];
      am = fmaf(f, m1_w[r * 64 + l], am);
      ac = fmaf(f, c1_w[r * 64 + l], ac);
    }
    float s1 = am, s2 = am * am;
    for (int m = 1; m < 64; m <<= 1) { s1 += __shfl_xor(s1, m); s2 += __shfl_xor(s2, m); }
    float mean = s1 * (1.f / 64.f), var = s2 * (1.f / 64.f) - mean * mean;
    sh_t1[w][0][l] = fmaxf((am - mean) * rsqrtf(var + 1e-5f) * m1_lg[l] + m1_lb[l], 0.f);
    s1 = ac; s2 = ac * ac;
    for (int m = 1; m < 64; m <<= 1) { s1 += __shfl_xor(s1, m); s2 += __shfl_xor(s2, m); }
    mean = s1 * (1.f / 64.f); var = s2 * (1.f / 64.f) - mean * mean;
    sh_t1[w][1][l] = fmaxf((ac - mean) * rsqrtf(var + 1e-5f) * c1_lg[l] + c1_lb[l], 0.f);
  }
  __syncthreads();

  // phase 5: tower layer 2 (lanes 0-31 motor, 32-63 cognitive) + output
  {
    int tw = l >> 5, c = l & 31;
    const float* w2  = tw ? c2_w  : m2_w;
    const float* b2  = tw ? c2_b  : m2_b;
    const float* lg2 = tw ? c2_lg : m2_lg;
    const float* lb2 = tw ? c2_lb : m2_lb;
    float a2 = b2[c];
    for (int r = 0; r < 64; r++) a2 = fmaf(sh_t1[w][tw][r], w2[r * 32 + c], a2);
    float u1 = a2, u2 = a2 * a2;
    for (int m = 1; m < 32; m <<= 1) {
      u1 += __shfl_xor(u1, m, 32);
      u2 += __shfl_xor(u2, m, 32);
    }
    float mean = u1 * (1.f / 32.f), var = u2 * (1.f / 32.f) - mean * mean;
    float y2 = fmaxf((a2 - mean) * rsqrtf(var + 1e-5f) * lg2[c] + lb2[c], 0.f);
    float p = y2 * (tw ? c3_w[c] : m3_w[c]);
    for (int m = 1; m < 32; m <<= 1) p += __shfl_xor(p, m, 32);
    if (c == 0) {
      float v = p + (tw ? c3_b[0] : m3_b[0]);
      if (tw) out[NN + i] = 1.f / (1.f + expf(-v));
      else    out[i] = v;
    }
  }
}

extern "C" void kernel_launch(void* const* d_in, const int* in_sizes, int n_in,
                              void* d_out, int out_size, void* d_ws, size_t ws_size,
                              hipStream_t stream) {
  (void)in_sizes; (void)n_in; (void)out_size;
  const float* spatial  = (const float*)d_in[0];
  const float* genomic  = (const float*)d_in[1];
  const float* temporal = (const float*)d_in[2];
  const int*   adj      = (const int*)d_in[3];
  const float* sp_w = (const float*)d_in[4];
  const float* sp_b = (const float*)d_in[5];
  const float* sp_lg = (const float*)d_in[6];
  const float* sp_lb = (const float*)d_in[7];
  const float* ge_w = (const float*)d_in[8];
  const float* ge_b = (const float*)d_in[9];
  const float* ge_lg = (const float*)d_in[10];
  const float* ge_lb = (const float*)d_in[11];
  const float* te_w = (const float*)d_in[12];
  const float* te_b = (const float*)d_in[13];
  const float* te_lg = (const float*)d_in[14];
  const float* te_lb = (const float*)d_in[15];
  const float* gat_w = (const float*)d_in[16];
  const float* gat_a = (const float*)d_in[17];
  const float* gat_ow = (const float*)d_in[18];
  const float* gat_ob = (const float*)d_in[19];
  const float* gat_lg = (const float*)d_in[20];
  const float* gat_lb = (const float*)d_in[21];
  const float* mha_iw = (const float*)d_in[22];
  const float* mha_ib = (const float*)d_in[23];
  const float* mha_ow = (const float*)d_in[24];
  const float* mha_ob = (const float*)d_in[25];
  const float* m1_w = (const float*)d_in[26];
  const float* m1_b = (const float*)d_in[27];
  const float* m1_lg = (const float*)d_in[28];
  const float* m1_lb = (const float*)d_in[29];
  const float* m2_w = (const float*)d_in[30];
  const float* m2_b = (const float*)d_in[31];
  const float* m2_lg = (const float*)d_in[32];
  const float* m2_lb = (const float*)d_in[33];
  const float* m3_w = (const float*)d_in[34];
  const float* m3_b = (const float*)d_in[35];
  const float* c1_w = (const float*)d_in[36];
  const float* c1_b = (const float*)d_in[37];
  const float* c1_lg = (const float*)d_in[38];
  const float* c1_lb = (const float*)d_in[39];
  const float* c2_w = (const float*)d_in[40];
  const float* c2_b = (const float*)d_in[41];
  const float* c2_lg = (const float*)d_in[42];
  const float* c2_lb = (const float*)d_in[43];
  const float* c3_w = (const float*)d_in[44];
  const float* c3_b = (const float*)d_in[45];

  float* ws  = (float*)d_ws;
  float* out = (float*)d_out;

  // pick NS (j-slices): part = NS*2*NN*64 floats, lpart = NS*2*NN*2 floats
  int NS = 16;
  while (NS > 1) {
    size_t need = (size_t)(OFF_PART + (size_t)NS * 2 * NN * 64 + (size_t)NS * 2 * NN * 2) * 4;
    if (need <= ws_size) break;
    NS >>= 1;
  }
  float* part  = ws + OFF_PART;
  float* lpart = part + (size_t)NS * 2 * NN * 64;

  k_pack<<<(NN * NN) / 256, 256, 0, stream>>>(adj, (unsigned long long*)(ws + OFF_PACK));
  k_embed<<<NN, 128, 0, stream>>>(spatial, genomic, temporal,
                                  sp_w, sp_b, sp_lg, sp_lb,
                                  ge_w, ge_b, ge_lg, ge_lb,
                                  te_w, te_b, te_lg, te_lb,
                                  gat_w, gat_a, ws);
  k_prep<<<34, 128, 0, stream>>>(mha_iw, mha_ib, mha_ow, mha_ob, ws);
  dim3 g2(NN / 64, NS);
  k_gat2<<<g2, 256, 0, stream>>>((const unsigned long long*)(ws + OFF_PACK),
                                 ws + OFF_HMAT, ws + OFF_F1, ws + OFF_F2,
                                 ws + OFF_MAXF2, part, lpart, NS);
  k_post2<<<NN / 2, 128, 0, stream>>>(gat_ow, gat_ob, gat_lg, gat_lb,
                                      m1_w, m1_b, m1_lg, m1_lb,
                                      m2_w, m2_b, m2_lg, m2_lb,
                                      m3_w, m3_b,
                                      c1_w, c1_b, c1_lg, c1_lb,
                                      c2_w, c2_b, c2_lg, c2_lb,
                                      c3_w, c3_b,
                                      part, lpart, ws + OFF_COMB,
                                      ws + OFF_W2, ws + OFF_B2,
                                      out, NS);
}

// Round 3
// 261.512 us; speedup vs baseline: 1.9887x; 1.5975x over previous
//
#include <hip/hip_runtime.h>
#include <math.h>

#define NN 4096
#define LOG2E 1.4426950408889634f

typedef short short8 __attribute__((ext_vector_type(8)));
typedef float f32x4 __attribute__((ext_vector_type(4)));

// workspace layout (float offsets)
#define OFF_COMB   0u          // 4096*96 = 393216
#define OFF_F1     393216u     // 2*4096 (head-major: f1h[head][i])
#define OFF_F2     401408u     // 2*4096 (head-major: f2h[head][j])
#define OFF_MAXF2  409600u     // 2 (+pad 16)
#define OFF_W2     409616u     // 32*96 = 3072
#define OFF_B2     412688u     // 96 (+pad to 412800)
#define OFF_HT     412800u     // bf16 hmatT[64][4096] = 262144 ushort = 131072 float slots
#define OFF_PART   543872u     // NS*NN*64 floats, then lpart NS*NN*2

__device__ inline unsigned short f2bf(float x) {
  unsigned u = __float_as_uint(x);
  unsigned r = u + 0x7FFFu + ((u >> 16) & 1u);   // RNE
  return (unsigned short)(r >> 16);
}

// ---------------- Kernel 1: embeddings + GAT projection + f1/f2 + hT ----------
__global__ __launch_bounds__(128) void k_embed(
    const float* __restrict__ spatial, const float* __restrict__ genomic,
    const float* __restrict__ temporal,
    const float* __restrict__ sp_w, const float* __restrict__ sp_b,
    const float* __restrict__ sp_lg, const float* __restrict__ sp_lb,
    const float* __restrict__ ge_w, const float* __restrict__ ge_b,
    const float* __restrict__ ge_lg, const float* __restrict__ ge_lb,
    const float* __restrict__ te_w, const float* __restrict__ te_b,
    const float* __restrict__ te_lg, const float* __restrict__ te_lb,
    const float* __restrict__ gat_w, const float* __restrict__ gat_a,
    float* __restrict__ ws)
{
  int row = blockIdx.x;
  int t = threadIdx.x;
  __shared__ float comb[96];
  __shared__ float hbuf[64];

  if (t < 96) {
    int g = t >> 5, c = t & 31;
    float x;
    if (g == 0) {
      const float* in = spatial + (size_t)row * 256;
      float a = sp_b[c];
#pragma unroll 8
      for (int k = 0; k < 256; k++) a = fmaf(in[k], sp_w[k * 32 + c], a);
      x = a;
    } else if (g == 1) {
      const float* in = genomic + (size_t)row * 8;
      float a = ge_b[c];
#pragma unroll
      for (int k = 0; k < 8; k++) a = fmaf(in[k], ge_w[k * 32 + c], a);
      x = a;
    } else {
      const float* in = temporal + (size_t)row * 64;
      float a = te_b[c];
#pragma unroll 8
      for (int k = 0; k < 64; k++) a = fmaf(in[k], te_w[k * 32 + c], a);
      x = a;
    }
    float s1 = x, s2 = x * x;
    for (int m = 1; m < 32; m <<= 1) {
      s1 += __shfl_xor(s1, m, 32);
      s2 += __shfl_xor(s2, m, 32);
    }
    float mean = s1 * (1.f / 32.f);
    float var  = s2 * (1.f / 32.f) - mean * mean;
    float inv  = rsqrtf(var + 1e-5f);
    const float* lg = (g == 0) ? sp_lg : (g == 1) ? ge_lg : te_lg;
    const float* lb = (g == 0) ? sp_lb : (g == 1) ? ge_lb : te_lb;
    float y = (x - mean) * inv * lg[c] + lb[c];
    y = fmaxf(y, 0.f);
    comb[t] = y;
    ws[OFF_COMB + (size_t)row * 96 + t] = y;
  }
  __syncthreads();
  if (t < 64) {
    float a = 0.f;
#pragma unroll 8
    for (int r = 0; r < 96; r++) a = fmaf(comb[r], gat_w[r * 64 + t], a);
    hbuf[t] = a;
    // bf16 transpose: hT[d][j]
    ((unsigned short*)(ws + OFF_HT))[(size_t)t * NN + row] = f2bf(a);
  }
  __syncthreads();
  if (t < 4) {
    int head = t & 1;
    const float* av = gat_a + ((t >> 1) ? 32 : 0);
    float a = 0.f;
#pragma unroll
    for (int d = 0; d < 32; d++) a = fmaf(hbuf[head * 32 + d], av[d], a);
    if ((t >> 1) == 0) ws[OFF_F1 + head * NN + row] = a;
    else               ws[OFF_F2 + head * NN + row] = a;
  }
}

// -------- Kernel 1b: fold mha (tile->v->attn collapses to 32x96), maxf2 --------
__global__ __launch_bounds__(128) void k_prep(
    const float* __restrict__ mha_iw, const float* __restrict__ mha_ib,
    const float* __restrict__ mha_ow, const float* __restrict__ mha_ob,
    float* __restrict__ ws)
{
  int b = blockIdx.x, t = threadIdx.x;
  if (b < 32) {
    if (t < 96) {
      float a = 0.f;
      for (int r = 0; r < 96; r++) {
        float fw = mha_iw[(b)      * 288 + 192 + r]
                 + mha_iw[(b + 32) * 288 + 192 + r]
                 + mha_iw[(b + 64) * 288 + 192 + r];
        a = fmaf(fw, mha_ow[r * 96 + t], a);
      }
      ws[OFF_W2 + b * 96 + t] = a;
    }
  } else if (b == 32) {
    if (t < 96) {
      float a = mha_ob[t];
      for (int r = 0; r < 96; r++) a = fmaf(mha_ib[192 + r], mha_ow[r * 96 + t], a);
      ws[OFF_B2 + t] = a;
    }
  } else {
    __shared__ float red[128 * 2];
    float m0 = -1e30f, m1 = -1e30f;
    for (int k = t; k < NN; k += 128) {
      m0 = fmaxf(m0, ws[OFF_F2 + k]);
      m1 = fmaxf(m1, ws[OFF_F2 + NN + k]);
    }
    red[t * 2] = m0; red[t * 2 + 1] = m1;
    __syncthreads();
    if (t < 2) {
      float m = -1e30f;
      for (int k = 0; k < 128; k++) m = fmaxf(m, red[k * 2 + t]);
      ws[OFF_MAXF2 + t] = m;
    }
  }
}

// ---- Kernel 2: GAT via MFMA — scores computed directly in A-fragment layout ---
// wave wv handles i in [blk.x*64 + wv*16, +16); block handles j-slice blk.y.
__global__ __launch_bounds__(256) void k_gat3(
    const int* __restrict__ adj,
    const unsigned short* __restrict__ hT,   // bf16 [d=64][j=4096]
    const float* __restrict__ f1h,           // [head][i]
    const float* __restrict__ f2h,           // [head][j]
    const float* __restrict__ maxf2,
    float* __restrict__ part,                // [slot][i][d=64]
    float* __restrict__ lpart, int NS)       // [slot][i][head]
{
  int t = threadIdx.x;
  int lane = t & 63, wv = t >> 6;
  int quad = lane >> 4, mrow = lane & 15;
  int ib = blockIdx.x * 64 + wv * 16;
  int i_lane = ib + mrow;
  int slice = NN / NS;
  int jb = blockIdx.y * slice;

  float f1v0 = f1h[i_lane];
  float f1v1 = f1h[NN + i_lane];
  float s0 = f1v0 + maxf2[0], s1 = f1v1 + maxf2[1];
  float sh0 = fmaxf(s0, 0.2f * s0);
  float sh1 = fmaxf(s1, 0.2f * s1);
  float c00 = -sh0 * LOG2E;
  float c01 = -sh1 * LOG2E;

  f32x4 acc00 = {0.f, 0.f, 0.f, 0.f};
  f32x4 acc01 = {0.f, 0.f, 0.f, 0.f};
  f32x4 acc10 = {0.f, 0.f, 0.f, 0.f};
  f32x4 acc11 = {0.f, 0.f, 0.f, 0.f};
  float ls0 = 0.f, ls1 = 0.f;

  const int* adjRow = adj + (size_t)i_lane * NN;

#pragma unroll 2
  for (int jc = jb; jc < jb + slice; jc += 32) {
    int jq = jc + quad * 8;
    int4 am0 = *(const int4*)(adjRow + jq);
    int4 am1 = *(const int4*)(adjRow + jq + 4);
    float4 fa = *(const float4*)(f2h + jq);
    float4 fb = *(const float4*)(f2h + jq + 4);
    float4 fc = *(const float4*)(f2h + NN + jq);
    float4 fd = *(const float4*)(f2h + NN + jq + 4);
    short8 b00 = *(const short8*)(hT + (size_t)(mrow)      * NN + jq);
    short8 b01 = *(const short8*)(hT + (size_t)(16 + mrow) * NN + jq);
    short8 b10 = *(const short8*)(hT + (size_t)(32 + mrow) * NN + jq);
    short8 b11 = *(const short8*)(hT + (size_t)(48 + mrow) * NN + jq);

    float f2a[8] = {fa.x, fa.y, fa.z, fa.w, fb.x, fb.y, fb.z, fb.w};
    float f2b[8] = {fc.x, fc.y, fc.z, fc.w, fd.x, fd.y, fd.z, fd.w};
    int   amv[8] = {am0.x, am0.y, am0.z, am0.w, am1.x, am1.y, am1.z, am1.w};

    union { short8 v; unsigned short u[8]; } a0, a1;
#pragma unroll
    for (int k = 0; k < 8; k++) {
      float e0 = f1v0 + f2a[k];
      float le0 = fmaxf(e0, 0.2f * e0);
      float w0 = __builtin_amdgcn_exp2f(fmaf(le0, LOG2E, c00));
      float e1 = f1v1 + f2b[k];
      float le1 = fmaxf(e1, 0.2f * e1);
      float w1 = __builtin_amdgcn_exp2f(fmaf(le1, LOG2E, c01));
      w0 = amv[k] ? w0 : 0.f;
      w1 = amv[k] ? w1 : 0.f;
      ls0 += w0; ls1 += w1;
      a0.u[k] = f2bf(w0);
      a1.u[k] = f2bf(w1);
    }
    acc00 = __builtin_amdgcn_mfma_f32_16x16x32_bf16(a0.v, b00, acc00, 0, 0, 0);
    acc01 = __builtin_amdgcn_mfma_f32_16x16x32_bf16(a0.v, b01, acc01, 0, 0, 0);
    acc10 = __builtin_amdgcn_mfma_f32_16x16x32_bf16(a1.v, b10, acc10, 0, 0, 0);
    acc11 = __builtin_amdgcn_mfma_f32_16x16x32_bf16(a1.v, b11, acc11, 0, 0, 0);
  }

  // lsum: reduce over quads (lanes with same (lane&15))
  ls0 += __shfl_xor(ls0, 16); ls0 += __shfl_xor(ls0, 32);
  ls1 += __shfl_xor(ls1, 16); ls1 += __shfl_xor(ls1, 32);

  int slot = blockIdx.y;
  // C layout: col = lane&15, row = quad*4 + reg
#pragma unroll
  for (int r = 0; r < 4; r++) {
    int ig = ib + quad * 4 + r;
    float* p = part + ((size_t)(slot * NN + ig)) * 64;
    p[mrow]      = acc00[r];
    p[16 + mrow] = acc01[r];
    p[32 + mrow] = acc10[r];
    p[48 + mrow] = acc11[r];
  }
  if (lane < 16) {
    int ig = ib + lane;
    lpart[(size_t)(slot * NN + ig) * 2]     = ls0;
    lpart[(size_t)(slot * NN + ig) * 2 + 1] = ls1;
  }
}

// ---------------- Kernel 3: one wave per row — reduce + folded tail + towers ---
__global__ __launch_bounds__(128) void k_post2(
    const float* __restrict__ gat_ow, const float* __restrict__ gat_ob,
    const float* __restrict__ gat_lg, const float* __restrict__ gat_lb,
    const float* __restrict__ m1_w, const float* __restrict__ m1_b,
    const float* __restrict__ m1_lg, const float* __restrict__ m1_lb,
    const float* __restrict__ m2_w, const float* __restrict__ m2_b,
    const float* __restrict__ m2_lg, const float* __restrict__ m2_lb,
    const float* __restrict__ m3_w, const float* __restrict__ m3_b,
    const float* __restrict__ c1_w, const float* __restrict__ c1_b,
    const float* __restrict__ c1_lg, const float* __restrict__ c1_lb,
    const float* __restrict__ c2_w, const float* __restrict__ c2_b,
    const float* __restrict__ c2_lg, const float* __restrict__ c2_lb,
    const float* __restrict__ c3_w, const float* __restrict__ c3_b,
    const float* __restrict__ part, const float* __restrict__ lpart,
    const float* __restrict__ comb, const float* __restrict__ W2,
    const float* __restrict__ B2,
    float* __restrict__ out, int NS)
{
  int t = threadIdx.x;
  int w = t >> 6, l = t & 63;
  int i = blockIdx.x * 2 + w;
  int slots = NS;

  __shared__ float sh_h[2][64];
  __shared__ float sh_go[2][32];
  __shared__ float sh_fin[2][96];
  __shared__ float sh_t1[2][2][64];

  // phase 1: reduce partials
  float a = 0.f;
  for (int s = 0; s < slots; s++) a += part[((size_t)(s * NN + i)) * 64 + l];
  float l0 = 0.f, l1 = 0.f;
  for (int s = 0; s < slots; s++) {
    l0 += lpart[(size_t)(s * NN + i) * 2];
    l1 += lpart[(size_t)(s * NN + i) * 2 + 1];
  }
  sh_h[w][l] = a / (l < 32 ? l0 : l1);
  __syncthreads();

  // phase 2: gat_out = LN32(h_out @ gat_ow + ob)
  if (l < 32) {
    float acc = gat_ob[l];
    for (int r = 0; r < 64; r++) acc = fmaf(sh_h[w][r], gat_ow[r * 32 + l], acc);
    float s1 = acc, s2 = acc * acc;
    for (int m = 1; m < 32; m <<= 1) {
      s1 += __shfl_xor(s1, m, 32);
      s2 += __shfl_xor(s2, m, 32);
    }
    float mean = s1 * (1.f / 32.f), var = s2 * (1.f / 32.f) - mean * mean;
    sh_go[w][l] = (acc - mean) * rsqrtf(var + 1e-5f) * gat_lg[l] + gat_lb[l];
  }
  __syncthreads();

  // phase 3: final = gat_out @ W2 + B2 + combined
  {
    float accA = B2[l];
    for (int d = 0; d < 32; d++) accA = fmaf(sh_go[w][d], W2[d * 96 + l], accA);
    sh_fin[w][l] = accA + comb[(size_t)i * 96 + l];
    if (l < 32) {
      float accB = B2[64 + l];
      for (int d = 0; d < 32; d++) accB = fmaf(sh_go[w][d], W2[d * 96 + 64 + l], accB);
      sh_fin[w][64 + l] = accB + comb[(size_t)i * 96 + 64 + l];
    }
  }
  __syncthreads();

  // phase 4: tower layer 1 for both towers
  {
    float am = m1_b[l], ac = c1_b[l];
    for (int r = 0; r < 96; r++) {
      float f = sh_fin[w][r];
      am = fmaf(f, m1_w[r * 64 + l], am);
      ac = fmaf(f, c1_w[r * 64 + l], ac);
    }
    float s1 = am, s2 = am * am;
    for (int m = 1; m < 64; m <<= 1) { s1 += __shfl_xor(s1, m); s2 += __shfl_xor(s2, m); }
    float mean = s1 * (1.f / 64.f), var = s2 * (1.f / 64.f) - mean * mean;
    sh_t1[w][0][l] = fmaxf((am - mean) * rsqrtf(var + 1e-5f) * m1_lg[l] + m1_lb[l], 0.f);
    s1 = ac; s2 = ac * ac;
    for (int m = 1; m < 64; m <<= 1) { s1 += __shfl_xor(s1, m); s2 += __shfl_xor(s2, m); }
    mean = s1 * (1.f / 64.f); var = s2 * (1.f / 64.f) - mean * mean;
    sh_t1[w][1][l] = fmaxf((ac - mean) * rsqrtf(var + 1e-5f) * c1_lg[l] + c1_lb[l], 0.f);
  }
  __syncthreads();

  // phase 5: tower layer 2 (lanes 0-31 motor, 32-63 cognitive) + output
  {
    int tw = l >> 5, c = l & 31;
    const float* w2  = tw ? c2_w  : m2_w;
    const float* b2  = tw ? c2_b  : m2_b;
    const float* lg2 = tw ? c2_lg : m2_lg;
    const float* lb2 = tw ? c2_lb : m2_lb;
    float a2 = b2[c];
    for (int r = 0; r < 64; r++) a2 = fmaf(sh_t1[w][tw][r], w2[r * 32 + c], a2);
    float u1 = a2, u2 = a2 * a2;
    for (int m = 1; m < 32; m <<= 1) {
      u1 += __shfl_xor(u1, m, 32);
      u2 += __shfl_xor(u2, m, 32);
    }
    float mean = u1 * (1.f / 32.f), var = u2 * (1.f / 32.f) - mean * mean;
    float y2 = fmaxf((a2 - mean) * rsqrtf(var + 1e-5f) * lg2[c] + lb2[c], 0.f);
    float p = y2 * (tw ? c3_w[c] : m3_w[c]);
    for (int m = 1; m < 32; m <<= 1) p += __shfl_xor(p, m, 32);
    if (c == 0) {
      float v = p + (tw ? c3_b[0] : m3_b[0]);
      if (tw) out[NN + i] = 1.f / (1.f + expf(-v));
      else    out[i] = v;
    }
  }
}

extern "C" void kernel_launch(void* const* d_in, const int* in_sizes, int n_in,
                              void* d_out, int out_size, void* d_ws, size_t ws_size,
                              hipStream_t stream) {
  (void)in_sizes; (void)n_in; (void)out_size;
  const float* spatial  = (const float*)d_in[0];
  const float* genomic  = (const float*)d_in[1];
  const float* temporal = (const float*)d_in[2];
  const int*   adj      = (const int*)d_in[3];
  const float* sp_w = (const float*)d_in[4];
  const float* sp_b = (const float*)d_in[5];
  const float* sp_lg = (const float*)d_in[6];
  const float* sp_lb = (const float*)d_in[7];
  const float* ge_w = (const float*)d_in[8];
  const float* ge_b = (const float*)d_in[9];
  const float* ge_lg = (const float*)d_in[10];
  const float* ge_lb = (const float*)d_in[11];
  const float* te_w = (const float*)d_in[12];
  const float* te_b = (const float*)d_in[13];
  const float* te_lg = (const float*)d_in[14];
  const float* te_lb = (const float*)d_in[15];
  const float* gat_w = (const float*)d_in[16];
  const float* gat_a = (const float*)d_in[17];
  const float* gat_ow = (const float*)d_in[18];
  const float* gat_ob = (const float*)d_in[19];
  const float* gat_lg = (const float*)d_in[20];
  const float* gat_lb = (const float*)d_in[21];
  const float* mha_iw = (const float*)d_in[22];
  const float* mha_ib = (const float*)d_in[23];
  const float* mha_ow = (const float*)d_in[24];
  const float* mha_ob = (const float*)d_in[25];
  const float* m1_w = (const float*)d_in[26];
  const float* m1_b = (const float*)d_in[27];
  const float* m1_lg = (const float*)d_in[28];
  const float* m1_lb = (const float*)d_in[29];
  const float* m2_w = (const float*)d_in[30];
  const float* m2_b = (const float*)d_in[31];
  const float* m2_lg = (const float*)d_in[32];
  const float* m2_lb = (const float*)d_in[33];
  const float* m3_w = (const float*)d_in[34];
  const float* m3_b = (const float*)d_in[35];
  const float* c1_w = (const float*)d_in[36];
  const float* c1_b = (const float*)d_in[37];
  const float* c1_lg = (const float*)d_in[38];
  const float* c1_lb = (const float*)d_in[39];
  const float* c2_w = (const float*)d_in[40];
  const float* c2_b = (const float*)d_in[41];
  const float* c2_lg = (const float*)d_in[42];
  const float* c2_lb = (const float*)d_in[43];
  const float* c3_w = (const float*)d_in[44];
  const float* c3_b = (const float*)d_in[45];

  float* ws  = (float*)d_ws;
  float* out = (float*)d_out;

  // NS j-slices: part = NS*NN*64 floats, lpart = NS*NN*2 floats
  int NS = 8;
  while (NS > 1) {
    size_t need = (size_t)(OFF_PART + (size_t)NS * NN * 64 + (size_t)NS * NN * 2) * 4;
    if (need <= ws_size) break;
    NS >>= 1;
  }
  float* part  = ws + OFF_PART;
  float* lpart = part + (size_t)NS * NN * 64;

  k_embed<<<NN, 128, 0, stream>>>(spatial, genomic, temporal,
                                  sp_w, sp_b, sp_lg, sp_lb,
                                  ge_w, ge_b, ge_lg, ge_lb,
                                  te_w, te_b, te_lg, te_lb,
                                  gat_w, gat_a, ws);
  k_prep<<<34, 128, 0, stream>>>(mha_iw, mha_ib, mha_ow, mha_ob, ws);
  dim3 g2(NN / 64, NS);
  k_gat3<<<g2, 256, 0, stream>>>(adj,
                                 (const unsigned short*)(ws + OFF_HT),
                                 ws + OFF_F1, ws + OFF_F2, ws + OFF_MAXF2,
                                 part, lpart, NS);
  k_post2<<<NN / 2, 128, 0, stream>>>(gat_ow, gat_ob, gat_lg, gat_lb,
                                      m1_w, m1_b, m1_lg, m1_lb,
                                      m2_w, m2_b, m2_lg, m2_lb,
                                      m3_w, m3_b,
                                      c1_w, c1_b, c1_lg, c1_lb,
                                      c2_w, c2_b, c2_lg, c2_lb,
                                      c3_w, c3_b,
                                      part, lpart, ws + OFF_COMB,
                                      ws + OFF_W2, ws + OFF_B2,
                                      out, NS);
}